// Round 1
// baseline (465.279 us; speedup 1.0000x reference)
//
#include <hip/hip_runtime.h>
#include <hip/hip_bf16.h>
#include <cstdint>

#define DI __device__ __forceinline__

typedef float f32x4 __attribute__((ext_vector_type(4)));
typedef short bf16x8 __attribute__((ext_vector_type(8)));

constexpr int B_ = 8, C_ = 256, HH = 48, WW = 48, N_ = 2304, CR = 32;
constexpr float QK_SCALE = 0.17677669529663687f;   // 32^-0.5
constexpr float BN_SC = 0.99999500003749968f;      // 1/sqrt(1+1e-5)

// ---------------- workspace layout (bytes) ----------------
constexpr size_t QK_SZ   = (size_t)B_*N_*CR*2;         // 1,179,648  (bf16 [B][N][32])
constexpr size_t V_SZ    = (size_t)B_*C_*N_*2;         // 9,437,184  (bf16 [B][C][N])
constexpr size_t OFF_RQT = 0;
constexpr size_t OFF_RKT = OFF_RQT + QK_SZ;
constexpr size_t OFF_DQT = OFF_RKT + QK_SZ;
constexpr size_t OFF_DKT = OFF_DQT + QK_SZ;
constexpr size_t OFF_RV  = OFF_DKT + QK_SZ;
constexpr size_t OFF_DV  = OFF_RV + V_SZ;
constexpr size_t OFF_ATT = OFF_DV + V_SZ;              // bf16 [B][512][N] (rows 0-255 rgb_att, 256-511 chm_att)
constexpr size_t ATT_SZ  = (size_t)B_*2*C_*N_*2;
constexpr size_t OFF_FUSED = OFF_RV;                   // reuse rv (dead after phase B); bf16 [B][C][N]
constexpr size_t OFF_SCONV = OFF_ATT + ATT_SZ;         // f32 [2][B][2][N]
constexpr size_t SCONV_SZ  = 2ull*B_*2*N_*4;
constexpr size_t OFF_SA    = OFF_SCONV + SCONV_SZ;     // f32 [2][B][N]
constexpr size_t SA_SZ     = 2ull*B_*N_*4;
constexpr size_t OFF_CAVG  = OFF_SA + SA_SZ;           // f32 [2][B][C]
constexpr size_t CST_SZ    = 2ull*B_*C_*4;
constexpr size_t OFF_CMAX  = OFF_CAVG + CST_SZ;
constexpr size_t OFF_CA    = OFF_CMAX + CST_SZ;
constexpr size_t OFF_M     = OFF_CA + CST_SZ;          // f32 [2][B][N]
constexpr size_t ML_SZ     = 2ull*B_*N_*4;
constexpr size_t OFF_LINV  = OFF_M + ML_SZ;
constexpr size_t OFF_WMAP  = OFF_LINV + ML_SZ;         // f32 [B][N]
constexpr size_t OFF_WPROJ = OFF_WMAP + (size_t)B_*N_*4;  // bf16 [2][320][256]
constexpr size_t WPROJ_SZ  = 2ull*320*256*2;
constexpr size_t OFF_WGATE = OFF_WPROJ + WPROJ_SZ;     // bf16 [256][512]
constexpr size_t WS_NEEDED = OFF_WGATE + 256ull*512*2; // ~41.9 MiB

DI float bf2f(unsigned short u){ union{unsigned int i; float f;} v; v.i = ((unsigned int)u)<<16; return v.f; }
DI unsigned short f2bf(float f){ union{float f; unsigned int i;} v; v.f=f; unsigned int r = v.i + 0x7fffu + ((v.i>>16)&1u); return (unsigned short)(r>>16); }
DI float sigm(float x){ return 1.0f/(1.0f+__expf(-x)); }

// ---------------- 1. cast/stack weights to bf16 ----------------
__global__ void k_prep_w(const float* rq_w, const float* rk_w, const float* rv_w,
                         const float* dq_w, const float* dk_w, const float* dv_w,
                         const float* gate_w, unsigned short* wproj, unsigned short* wgate){
  int i = blockIdx.x*256 + threadIdx.x;
  if (i < 163840){
    int mod = i / 81920, r = (i >> 8) % 320, c = i & 255;
    const float* q = mod ? dq_w : rq_w;
    const float* k = mod ? dk_w : rk_w;
    const float* v = mod ? dv_w : rv_w;
    float val = (r < 32) ? q[r*256+c] : (r < 64 ? k[(r-32)*256+c] : v[(r-64)*256+c]);
    wproj[i] = f2bf(val);
  } else {
    int j = i - 163840;
    if (j < 131072) wgate[j] = f2bf(gate_w[j]);
  }
}

// ---------------- 2. per-pixel channel mean/max (spatial-attn input) ----------------
__global__ void k_red_spatial(const float* rgb, const float* chm, float* sconv){
  int mod = blockIdx.y;
  const float* X = mod ? chm : rgb;
  int b = blockIdx.x / (N_/64);
  int pix0 = (blockIdx.x % (N_/64)) * 64;
  int p = threadIdx.x & 63, g = threadIdx.x >> 6;
  const float* base = X + (size_t)b*C_*N_ + pix0 + p;
  float s = 0.f, mx = -INFINITY;
  for (int c = g*64; c < g*64+64; ++c){ float v = base[(size_t)c*N_]; s += v; mx = fmaxf(mx, v); }
  __shared__ float ls[4][64], lm[4][64];
  ls[g][p] = s; lm[g][p] = mx;
  __syncthreads();
  if (g == 0){
    s = ls[0][p]+ls[1][p]+ls[2][p]+ls[3][p];
    mx = fmaxf(fmaxf(lm[0][p],lm[1][p]), fmaxf(lm[2][p],lm[3][p]));
    sconv[((size_t)(mod*B_+b)*2 + 0)*N_ + pix0+p] = s*(1.f/256.f);
    sconv[((size_t)(mod*B_+b)*2 + 1)*N_ + pix0+p] = mx;
  }
}

// ---------------- 3. per-channel spatial mean/max (channel-attn input) ----------------
__global__ void k_red_channel(const float* rgb, const float* chm, float* cavg, float* cmax){
  int mod = blockIdx.y;
  const float* X = mod ? chm : rgb;
  int b = blockIdx.x >> 8, c = blockIdx.x & 255;
  const float* base = X + ((size_t)b*C_ + c)*N_;
  float s = 0.f, mx = -INFINITY;
  for (int i = threadIdx.x; i < N_; i += 256){ float v = base[i]; s += v; mx = fmaxf(mx, v); }
  for (int m = 32; m; m >>= 1){ s += __shfl_xor(s, m); mx = fmaxf(mx, __shfl_xor(mx, m)); }
  __shared__ float ss[4], sm[4];
  int w = threadIdx.x >> 6;
  if ((threadIdx.x & 63) == 0){ ss[w] = s; sm[w] = mx; }
  __syncthreads();
  if (threadIdx.x == 0){
    s = ss[0]+ss[1]+ss[2]+ss[3];
    mx = fmaxf(fmaxf(sm[0],sm[1]), fmaxf(sm[2],sm[3]));
    cavg[(mod*B_+b)*C_ + c] = s*(1.f/(float)N_);
    cmax[(mod*B_+b)*C_ + c] = mx;
  }
}

// ---------------- 4. 7x7 conv (2->1) + sigmoid ----------------
__global__ void k_conv7(const float* sconv, const float* rgb_sa_w, const float* rgb_sa_b,
                        const float* chm_sa_w, const float* chm_sa_b, float* sa){
  int mod = blockIdx.y;
  int idx = blockIdx.x*256 + threadIdx.x;
  int b = idx / N_, pix = idx % N_;
  int y = pix / WW, x = pix % WW;
  const float* w7 = mod ? chm_sa_w : rgb_sa_w;
  float acc = (mod ? chm_sa_b : rgb_sa_b)[0];
  const float* sin0 = sconv + (size_t)(mod*B_+b)*2*N_;
  #pragma unroll
  for (int ic = 0; ic < 2; ++ic)
    for (int ky = 0; ky < 7; ++ky){
      int yy = y + ky - 3; if (yy < 0 || yy >= HH) continue;
      for (int kx = 0; kx < 7; ++kx){
        int xx = x + kx - 3; if (xx < 0 || xx >= WW) continue;
        acc += w7[(ic*7+ky)*7+kx] * sin0[ic*N_ + yy*WW + xx];
      }
    }
  sa[(mod*B_+b)*N_ + pix] = sigm(acc);
}

// ---------------- 5. channel-attn MLP ----------------
__global__ void k_ca(const float* cavg, const float* cmax,
                     const float* rw1, const float* rb1, const float* rw2, const float* rb2,
                     const float* cw1, const float* cb1, const float* cw2, const float* cb2,
                     float* ca){
  int mod = blockIdx.x >> 3, b = blockIdx.x & 7;
  const float* w1 = mod ? cw1 : rw1;  const float* b1 = mod ? cb1 : rb1;
  const float* w2 = mod ? cw2 : rw2;  const float* b2 = mod ? cb2 : rb2;
  __shared__ float va[256], vm[256], h1a[16], h1m[16];
  int t = threadIdx.x;
  va[t] = cavg[(mod*B_+b)*C_ + t];
  vm[t] = cmax[(mod*B_+b)*C_ + t];
  __syncthreads();
  if (t < 32){
    int j = t & 15;
    const float* v = (t >= 16) ? vm : va;
    float s = b1[j];
    for (int c = 0; c < 256; ++c) s += w1[j*256+c]*v[c];
    float* hp = (t >= 16) ? h1m : h1a;
    hp[j] = fmaxf(s, 0.f);
  }
  __syncthreads();
  float fa = b2[t], fm = b2[t];
  #pragma unroll
  for (int j = 0; j < 16; ++j){ fa += w2[t*16+j]*h1a[j]; fm += w2[t*16+j]*h1m[j]; }
  ca[(mod*B_+b)*C_ + t] = sigm(fa + fm);
}

// ---------------- 6. q/k/v projections (MFMA), q/k stored transposed ----------------
__global__ void k_proj(const float* rgb, const float* chm, const unsigned short* wproj,
                       const float* rq_b, const float* rk_b, const float* rv_b,
                       const float* dq_b, const float* dk_b, const float* dv_b,
                       unsigned short* wsu){
  int mod = blockIdx.z, b = blockIdx.y;
  int pix0 = blockIdx.x * 64;
  const float* X = (mod ? chm : rgb) + (size_t)b*C_*N_;
  const unsigned short* Wm = wproj + (size_t)mod*320*256;
  int lane = threadIdx.x & 63, w = threadIdx.x >> 6;
  int l15 = lane & 15, g = lane >> 4;
  f32x4 acc[5][4];
  #pragma unroll
  for (int i = 0; i < 5; ++i)
    #pragma unroll
    for (int j = 0; j < 4; ++j) acc[i][j] = 0.f;
  for (int k0 = 0; k0 < 256; k0 += 32){
    bf16x8 af[5];
    #pragma unroll
    for (int cf = 0; cf < 5; ++cf)
      af[cf] = *(const bf16x8*)(Wm + (size_t)(w*80 + cf*16 + l15)*256 + k0 + g*8);
    bf16x8 bx[4];
    #pragma unroll
    for (int mf = 0; mf < 4; ++mf){
      const float* xp = X + (size_t)(k0 + g*8)*N_ + pix0 + mf*16 + l15;
      #pragma unroll
      for (int j = 0; j < 8; ++j) bx[mf][j] = (short)f2bf(xp[(size_t)j*N_]);
    }
    #pragma unroll
    for (int cf = 0; cf < 5; ++cf)
      #pragma unroll
      for (int mf = 0; mf < 4; ++mf)
        acc[cf][mf] = __builtin_amdgcn_mfma_f32_16x16x32_bf16(af[cf], bx[mf], acc[cf][mf], 0, 0, 0);
  }
  const float* qb = mod ? dq_b : rq_b;
  const float* kb = mod ? dk_b : rk_b;
  const float* vb = mod ? dv_b : rv_b;
  unsigned short* qT = wsu + (mod ? OFF_DQT : OFF_RQT)/2;
  unsigned short* kT = wsu + (mod ? OFF_DKT : OFF_RKT)/2;
  unsigned short* vB = wsu + (mod ? OFF_DV  : OFF_RV )/2;
  #pragma unroll
  for (int cf = 0; cf < 5; ++cf)
    #pragma unroll
    for (int mf = 0; mf < 4; ++mf){
      int col = pix0 + mf*16 + l15;
      #pragma unroll
      for (int r = 0; r < 4; ++r){
        int o = w*80 + cf*16 + g*4 + r;
        float v = acc[cf][mf][r];
        if (o < 32)       qT[(size_t)(b*N_ + col)*32 + o]        = f2bf(v + qb[o]);
        else if (o < 64)  kT[(size_t)(b*N_ + col)*32 + (o-32)]   = f2bf(v + kb[o-32]);
        else              vB[((size_t)b*C_ + (o-64))*N_ + col]   = f2bf(v + vb[o-64]);
      }
    }
}

// ---------------- 7. softmax row stats (online max / sum over m) ----------------
__global__ void k_phase_a(const unsigned short* wsu, float* Mbuf, float* Linv){
  int a = blockIdx.z, b = blockIdx.y;
  int lane = threadIdx.x & 63, w = threadIdx.x >> 6;
  int l15 = lane & 15, g = lane >> 4;
  int n0 = blockIdx.x*64 + w*16;
  const unsigned short* Q = wsu + (a ? OFF_DQT : OFF_RQT)/2;   // rgb_attn: rq ; chm_attn: dq
  const unsigned short* K = wsu + (a ? OFF_RKT : OFF_DKT)/2;   // rgb_attn: dk ; chm_attn: rk
  bf16x8 af = *(const bf16x8*)(Q + (size_t)(b*N_ + n0 + l15)*32 + g*8);
  float mrun[4] = {-INFINITY,-INFINITY,-INFINITY,-INFINITY};
  float lrun[4] = {0.f,0.f,0.f,0.f};
  for (int m0 = 0; m0 < N_; m0 += 64){
    f32x4 d[4];
    #pragma unroll
    for (int s = 0; s < 4; ++s){
      bf16x8 bk = *(const bf16x8*)(K + (size_t)(b*N_ + m0 + s*16 + l15)*32 + g*8);
      f32x4 z = 0.f;
      d[s] = __builtin_amdgcn_mfma_f32_16x16x32_bf16(af, bk, z, 0, 0, 0);
    }
    #pragma unroll
    for (int r = 0; r < 4; ++r){
      float tm = fmaxf(fmaxf(d[0][r], d[1][r]), fmaxf(d[2][r], d[3][r])) * QK_SCALE;
      #pragma unroll
      for (int msk = 1; msk < 16; msk <<= 1) tm = fmaxf(tm, __shfl_xor(tm, msk));
      float nm = fmaxf(mrun[r], tm);
      float ps = 0.f;
      #pragma unroll
      for (int s = 0; s < 4; ++s) ps += __expf(d[s][r]*QK_SCALE - nm);
      #pragma unroll
      for (int msk = 1; msk < 16; msk <<= 1) ps += __shfl_xor(ps, msk);
      lrun[r] = lrun[r]*__expf(mrun[r] - nm) + ps;
      mrun[r] = nm;
    }
  }
  if (l15 == 0){
    #pragma unroll
    for (int r = 0; r < 4; ++r){
      int n = n0 + g*4 + r;
      Mbuf[(a*B_+b)*N_ + n] = mrun[r];
      Linv[(a*B_+b)*N_ + n] = 1.0f / lrun[r];
    }
  }
}

// ---------------- 8. attention phase B: out = V @ softmax-normalized P ----------------
__global__ void k_phase_b(const unsigned short* wsu, const float* Mbuf, const float* Linv,
                          unsigned short* att){
  int a = blockIdx.z, b = blockIdx.y;
  int mblk = blockIdx.x % 36, cblk = blockIdx.x / 36;
  int m0 = mblk*64, c0 = cblk*128;
  int lane = threadIdx.x & 63, w = threadIdx.x >> 6;
  int l15 = lane & 15, g = lane >> 4;
  int nf = w & 1;
  int msub = (w >> 1) * 32;
  int csub = (w & 1) * 64;
  const unsigned short* Q = wsu + (a ? OFF_DQT : OFF_RQT)/2;
  const unsigned short* K = wsu + (a ? OFF_RKT : OFF_DKT)/2;
  const unsigned short* V = wsu + (a ? OFF_DV  : OFF_RV )/2;
  const float* Mr = Mbuf + (size_t)(a*B_+b)*N_;
  const float* Lr = Linv + (size_t)(a*B_+b)*N_;
  __shared__ unsigned short plds[64*40];   // [m_local 64][n_local 32], stride 40 (80B rows)
  bf16x8 kb[2];
  #pragma unroll
  for (int s = 0; s < 2; ++s)
    kb[s] = *(const bf16x8*)(K + (size_t)(b*N_ + m0 + msub + s*16 + l15)*32 + g*8);
  f32x4 acc[4][2];
  #pragma unroll
  for (int i = 0; i < 4; ++i){ acc[i][0] = 0.f; acc[i][1] = 0.f; }
  for (int n0 = 0; n0 < N_; n0 += 32){
    bf16x8 qa = *(const bf16x8*)(Q + (size_t)(b*N_ + n0 + nf*16 + l15)*32 + g*8);
    float M4[4], L4[4];
    #pragma unroll
    for (int r = 0; r < 4; ++r){ int n = n0 + nf*16 + g*4 + r; M4[r] = Mr[n]; L4[r] = Lr[n]; }
    #pragma unroll
    for (int s = 0; s < 2; ++s){
      f32x4 z = 0.f;
      f32x4 d = __builtin_amdgcn_mfma_f32_16x16x32_bf16(qa, kb[s], z, 0, 0, 0);
      int mloc = msub + s*16 + l15;
      #pragma unroll
      for (int r = 0; r < 4; ++r){
        float p = __expf(d[r]*QK_SCALE - M4[r]) * L4[r];
        plds[(size_t)mloc*40 + nf*16 + g*4 + r] = f2bf(p);
      }
    }
    __syncthreads();
    bf16x8 pb[2];
    #pragma unroll
    for (int s = 0; s < 2; ++s){
      const unsigned short* pp = plds + (size_t)(msub + s*16 + l15)*40 + g*8;
      union { unsigned long long q[2]; bf16x8 v; } u;
      u.q[0] = *(const unsigned long long*)pp;
      u.q[1] = *(const unsigned long long*)(pp + 4);
      pb[s] = u.v;
    }
    #pragma unroll
    for (int cf = 0; cf < 4; ++cf){
      bf16x8 av = *(const bf16x8*)(V + ((size_t)b*C_ + c0 + csub + cf*16 + l15)*N_ + n0 + g*8);
      #pragma unroll
      for (int s = 0; s < 2; ++s)
        acc[cf][s] = __builtin_amdgcn_mfma_f32_16x16x32_bf16(av, pb[s], acc[cf][s], 0, 0, 0);
    }
    __syncthreads();
  }
  #pragma unroll
  for (int cf = 0; cf < 4; ++cf)
    #pragma unroll
    for (int s = 0; s < 2; ++s)
      #pragma unroll
      for (int r = 0; r < 4; ++r){
        int c = c0 + csub + cf*16 + g*4 + r;
        int m = m0 + msub + s*16 + l15;
        att[((size_t)b*512 + a*256 + c)*N_ + m] = f2bf(acc[cf][s][r]);
      }
}

// ---------------- 9. gate GEMM (MFMA) + fuse ----------------
__global__ void k_gatefuse(const unsigned short* att, const unsigned short* wgate,
                           const float* gate_b, unsigned short* fused){
  int b = blockIdx.y, m0 = blockIdx.x*64;
  int lane = threadIdx.x & 63, w = threadIdx.x >> 6;
  int l15 = lane & 15, g = lane >> 4;
  f32x4 acc[4][4];
  #pragma unroll
  for (int i = 0; i < 4; ++i)
    #pragma unroll
    for (int j = 0; j < 4; ++j) acc[i][j] = 0.f;
  const unsigned short* cat = att + (size_t)b*512*N_;
  for (int k0 = 0; k0 < 512; k0 += 32){
    bf16x8 aw[4];
    #pragma unroll
    for (int of = 0; of < 4; ++of)
      aw[of] = *(const bf16x8*)(wgate + (size_t)(w*64 + of*16 + l15)*512 + k0 + g*8);
    bf16x8 cb[4];
    #pragma unroll
    for (int mf = 0; mf < 4; ++mf){
      const unsigned short* cp = cat + (size_t)(k0 + g*8)*N_ + m0 + mf*16 + l15;
      #pragma unroll
      for (int j = 0; j < 8; ++j) cb[mf][j] = (short)cp[(size_t)j*N_];
    }
    #pragma unroll
    for (int of = 0; of < 4; ++of)
      #pragma unroll
      for (int mf = 0; mf < 4; ++mf)
        acc[of][mf] = __builtin_amdgcn_mfma_f32_16x16x32_bf16(aw[of], cb[mf], acc[of][mf], 0, 0, 0);
  }
  #pragma unroll
  for (int of = 0; of < 4; ++of)
    #pragma unroll
    for (int mf = 0; mf < 4; ++mf)
      #pragma unroll
      for (int r = 0; r < 4; ++r){
        int o = w*64 + of*16 + g*4 + r;
        int m = m0 + mf*16 + l15;
        float gg = sigm(acc[of][mf][r] + gate_b[o]);
        float ra = bf2f(att[((size_t)b*512 + o)*N_ + m]);
        float da = bf2f(att[((size_t)b*512 + 256 + o)*N_ + m]);
        float fv = ra*gg + da*(1.f - gg) + ra*da;
        fused[((size_t)b*C_ + o)*N_ + m] = f2bf(fv);
      }
}

// ---------------- 10. mlp -> per-pixel weight ----------------
__global__ void k_mlp(const unsigned short* fused, const float* w1, const float* g1, const float* b1,
                      const float* w2, const float* g2, const float* b2, float* wmap){
  int idx = blockIdx.x*256 + threadIdx.x;
  int b = idx / N_, pix = idx % N_;
  float h[24];
  #pragma unroll
  for (int j = 0; j < 24; ++j) h[j] = 0.f;
  const unsigned short* fp = fused + (size_t)b*C_*N_ + pix;
  for (int c = 0; c < 256; ++c){
    float v = bf2f(fp[(size_t)c*N_]);
    #pragma unroll
    for (int j = 0; j < 24; ++j) h[j] += w1[j*256 + c] * v;
  }
  float s2 = 0.f;
  #pragma unroll
  for (int j = 0; j < 24; ++j){
    float hj = fmaxf(h[j]*(BN_SC*g1[j]) + b1[j], 0.f);
    s2 += w2[j]*hj;
  }
  s2 = s2*(BN_SC*g2[0]) + b2[0];
  wmap[idx] = sigm(sigm(s2));
}

// ---------------- 11. final combine ----------------
__global__ void k_final(const float* rgb, const float* chm, const float* sa, const float* ca,
                        const float* wmap, float* out){
  const int total4 = B_*C_*N_/4;
  for (int i = blockIdx.x*blockDim.x + threadIdx.x; i < total4; i += gridDim.x*blockDim.x){
    int e = i*4;
    int b = e / (C_*N_);
    int rem = e % (C_*N_);
    int c = rem / N_;
    int pix = rem % N_;
    float4 rv = *(const float4*)(rgb + e);
    float4 cv = *(const float4*)(chm + e);
    float4 sc = *(const float4*)(sa + (size_t)(B_ + b)*N_ + pix);  // chm_sa
    float4 sr = *(const float4*)(sa + (size_t)b*N_ + pix);         // rgb_sa
    float4 wm = *(const float4*)(wmap + (size_t)b*N_ + pix);
    float cac = ca[(B_ + b)*C_ + c];   // chm_ca
    float car = ca[b*C_ + c];          // rgb_ca
    float4 o;
    o.x = rv.x*sc.x*cac + cv.x*sr.x*car*wm.x;
    o.y = rv.y*sc.y*cac + cv.y*sr.y*car*wm.y;
    o.z = rv.z*sc.z*cac + cv.z*sr.z*car*wm.z;
    o.w = rv.w*sc.w*cac + cv.w*sr.w*car*wm.w;
    *(float4*)(out + e) = o;
  }
}

extern "C" void kernel_launch(void* const* d_in, const int* in_sizes, int n_in,
                              void* d_out, int out_size, void* d_ws, size_t ws_size,
                              hipStream_t stream){
  if (ws_size < WS_NEEDED) return;   // workspace too small; fail loudly via absmax
  const float* rgb      = (const float*)d_in[0];
  const float* chm      = (const float*)d_in[1];
  const float* rgb_sa_w = (const float*)d_in[2];
  const float* rgb_sa_b = (const float*)d_in[3];
  const float* chm_sa_w = (const float*)d_in[4];
  const float* chm_sa_b = (const float*)d_in[5];
  const float* rgb_fc1_w= (const float*)d_in[6];
  const float* rgb_fc1_b= (const float*)d_in[7];
  const float* rgb_fc2_w= (const float*)d_in[8];
  const float* rgb_fc2_b= (const float*)d_in[9];
  const float* chm_fc1_w= (const float*)d_in[10];
  const float* chm_fc1_b= (const float*)d_in[11];
  const float* chm_fc2_w= (const float*)d_in[12];
  const float* chm_fc2_b= (const float*)d_in[13];
  const float* rq_w = (const float*)d_in[14];
  const float* rq_b = (const float*)d_in[15];
  const float* rk_w = (const float*)d_in[16];
  const float* rk_b = (const float*)d_in[17];
  const float* rv_w = (const float*)d_in[18];
  const float* rv_b = (const float*)d_in[19];
  const float* dq_w = (const float*)d_in[20];
  const float* dq_b = (const float*)d_in[21];
  const float* dk_w = (const float*)d_in[22];
  const float* dk_b = (const float*)d_in[23];
  const float* dv_w = (const float*)d_in[24];
  const float* dv_b = (const float*)d_in[25];
  const float* gate_w = (const float*)d_in[26];
  const float* gate_b = (const float*)d_in[27];
  const float* mlp1_w = (const float*)d_in[28];
  const float* mlp1_g = (const float*)d_in[29];
  const float* mlp1_b = (const float*)d_in[30];
  const float* mlp2_w = (const float*)d_in[31];
  const float* mlp2_g = (const float*)d_in[32];
  const float* mlp2_b = (const float*)d_in[33];

  char* ws = (char*)d_ws;
  unsigned short* wsu   = (unsigned short*)d_ws;
  float* sconv = (float*)(ws + OFF_SCONV);
  float* sa    = (float*)(ws + OFF_SA);
  float* cavg  = (float*)(ws + OFF_CAVG);
  float* cmax  = (float*)(ws + OFF_CMAX);
  float* ca    = (float*)(ws + OFF_CA);
  float* Mbuf  = (float*)(ws + OFF_M);
  float* Linv  = (float*)(ws + OFF_LINV);
  float* wmap  = (float*)(ws + OFF_WMAP);
  unsigned short* wproj = (unsigned short*)(ws + OFF_WPROJ);
  unsigned short* wgate = (unsigned short*)(ws + OFF_WGATE);
  unsigned short* att   = (unsigned short*)(ws + OFF_ATT);
  unsigned short* fused = (unsigned short*)(ws + OFF_FUSED);

  k_prep_w<<<dim3(1152), dim3(256), 0, stream>>>(rq_w, rk_w, rv_w, dq_w, dk_w, dv_w, gate_w, wproj, wgate);
  k_red_spatial<<<dim3(288,2), dim3(256), 0, stream>>>(rgb, chm, sconv);
  k_red_channel<<<dim3(2048,2), dim3(256), 0, stream>>>(rgb, chm, cavg, cmax);
  k_conv7<<<dim3(72,2), dim3(256), 0, stream>>>(sconv, rgb_sa_w, rgb_sa_b, chm_sa_w, chm_sa_b, sa);
  k_ca<<<dim3(16), dim3(256), 0, stream>>>(cavg, cmax, rgb_fc1_w, rgb_fc1_b, rgb_fc2_w, rgb_fc2_b,
                                           chm_fc1_w, chm_fc1_b, chm_fc2_w, chm_fc2_b, ca);
  k_proj<<<dim3(36,8,2), dim3(256), 0, stream>>>(rgb, chm, wproj, rq_b, rk_b, rv_b, dq_b, dk_b, dv_b, wsu);
  k_phase_a<<<dim3(36,8,2), dim3(256), 0, stream>>>(wsu, Mbuf, Linv);
  k_phase_b<<<dim3(72,8,2), dim3(256), 0, stream>>>(wsu, Mbuf, Linv, att);
  k_gatefuse<<<dim3(36,8), dim3(256), 0, stream>>>(att, wgate, gate_b, fused);
  k_mlp<<<dim3(72), dim3(256), 0, stream>>>(fused, mlp1_w, mlp1_g, mlp1_b, mlp2_w, mlp2_g, mlp2_b, wmap);
  k_final<<<dim3(2048), dim3(256), 0, stream>>>(rgb, chm, sa, ca, wmap, (float*)d_out);
}

// Round 2
// 363.372 us; speedup vs baseline: 1.2804x; 1.2804x over previous
//
#include <hip/hip_runtime.h>
#include <hip/hip_bf16.h>
#include <cstdint>

#define DI __device__ __forceinline__

typedef float f32x4 __attribute__((ext_vector_type(4)));
typedef short bf16x8 __attribute__((ext_vector_type(8)));
typedef unsigned short u16x4 __attribute__((ext_vector_type(4)));

constexpr int B_ = 8, C_ = 256, HH = 48, WW = 48, N_ = 2304, CR = 32;
constexpr float QK_SCALE = 0.17677669529663687f;   // 32^-0.5
constexpr float BN_SC = 0.99999500003749968f;      // 1/sqrt(1+1e-5)

// ---------------- workspace layout (bytes) ----------------
constexpr size_t QK_SZ   = (size_t)B_*N_*CR*2;         // bf16 [B][N][32]
constexpr size_t V_SZ    = (size_t)B_*C_*N_*2;         // bf16 [B][C][N]
constexpr size_t OFF_RQT = 0;
constexpr size_t OFF_RKT = OFF_RQT + QK_SZ;
constexpr size_t OFF_DQT = OFF_RKT + QK_SZ;
constexpr size_t OFF_DKT = OFF_DQT + QK_SZ;
constexpr size_t OFF_RV  = OFF_DKT + QK_SZ;
constexpr size_t OFF_DV  = OFF_RV + V_SZ;
constexpr size_t OFF_ATT = OFF_DV + V_SZ;              // bf16 [B][512][N]
constexpr size_t ATT_SZ  = (size_t)B_*2*C_*N_*2;
constexpr size_t OFF_FUSED = OFF_RV;                   // reuse rv (dead after phase B)
constexpr size_t OFF_SCONV = OFF_ATT + ATT_SZ;         // f32 [2][B][2][N]
constexpr size_t SCONV_SZ  = 2ull*B_*2*N_*4;
constexpr size_t OFF_SA    = OFF_SCONV + SCONV_SZ;     // f32 [2][B][N]
constexpr size_t SA_SZ     = 2ull*B_*N_*4;
constexpr size_t OFF_CAVG  = OFF_SA + SA_SZ;           // f32 [2][B][C]
constexpr size_t CST_SZ    = 2ull*B_*C_*4;
constexpr size_t OFF_CMAX  = OFF_CAVG + CST_SZ;
constexpr size_t OFF_CA    = OFF_CMAX + CST_SZ;
constexpr size_t OFF_M     = OFF_CA + CST_SZ;          // f32 [2][B][N]
constexpr size_t ML_SZ     = 2ull*B_*N_*4;
constexpr size_t OFF_LINV  = OFF_M + ML_SZ;
constexpr size_t OFF_WMAP  = OFF_LINV + ML_SZ;         // f32 [B][N]
constexpr size_t OFF_WPROJ = OFF_WMAP + (size_t)B_*N_*4;  // bf16 [2][320][256]
constexpr size_t WPROJ_SZ  = 2ull*320*256*2;
constexpr size_t OFF_WGATE = OFF_WPROJ + WPROJ_SZ;     // bf16 [256][512]
constexpr size_t WS_NEEDED = OFF_WGATE + 256ull*512*2;

DI float bf2f(unsigned short u){ union{unsigned int i; float f;} v; v.i = ((unsigned int)u)<<16; return v.f; }
DI unsigned short f2bf(float f){ union{float f; unsigned int i;} v; v.f=f; unsigned int r = v.i + 0x7fffu + ((v.i>>16)&1u); return (unsigned short)(r>>16); }
DI float sigm(float x){ return 1.0f/(1.0f+__expf(-x)); }

// ---------------- 1. cast/stack weights to bf16 ----------------
__global__ void k_prep_w(const float* rq_w, const float* rk_w, const float* rv_w,
                         const float* dq_w, const float* dk_w, const float* dv_w,
                         const float* gate_w, unsigned short* wproj, unsigned short* wgate){
  int i = blockIdx.x*256 + threadIdx.x;
  if (i < 163840){
    int mod = i / 81920, r = (i >> 8) % 320, c = i & 255;
    const float* q = mod ? dq_w : rq_w;
    const float* k = mod ? dk_w : rk_w;
    const float* v = mod ? dv_w : rv_w;
    float val = (r < 32) ? q[r*256+c] : (r < 64 ? k[(r-32)*256+c] : v[(r-64)*256+c]);
    wproj[i] = f2bf(val);
  } else {
    int j = i - 163840;
    if (j < 131072) wgate[j] = f2bf(gate_w[j]);
  }
}

// ---------------- 2. per-pixel channel mean/max ----------------
__global__ void k_red_spatial(const float* rgb, const float* chm, float* sconv){
  int mod = blockIdx.y;
  const float* X = mod ? chm : rgb;
  int b = blockIdx.x / (N_/64);
  int pix0 = (blockIdx.x % (N_/64)) * 64;
  int p = threadIdx.x & 63, g = threadIdx.x >> 6;
  const float* base = X + (size_t)b*C_*N_ + pix0 + p;
  float s = 0.f, mx = -INFINITY;
  for (int c = g*64; c < g*64+64; ++c){ float v = base[(size_t)c*N_]; s += v; mx = fmaxf(mx, v); }
  __shared__ float ls[4][64], lm[4][64];
  ls[g][p] = s; lm[g][p] = mx;
  __syncthreads();
  if (g == 0){
    s = ls[0][p]+ls[1][p]+ls[2][p]+ls[3][p];
    mx = fmaxf(fmaxf(lm[0][p],lm[1][p]), fmaxf(lm[2][p],lm[3][p]));
    sconv[((size_t)(mod*B_+b)*2 + 0)*N_ + pix0+p] = s*(1.f/256.f);
    sconv[((size_t)(mod*B_+b)*2 + 1)*N_ + pix0+p] = mx;
  }
}

// ---------------- 3. per-channel spatial mean/max ----------------
__global__ void k_red_channel(const float* rgb, const float* chm, float* cavg, float* cmax){
  int mod = blockIdx.y;
  const float* X = mod ? chm : rgb;
  int b = blockIdx.x >> 8, c = blockIdx.x & 255;
  const float* base = X + ((size_t)b*C_ + c)*N_;
  float s = 0.f, mx = -INFINITY;
  for (int i = threadIdx.x; i < N_; i += 256){ float v = base[i]; s += v; mx = fmaxf(mx, v); }
  for (int m = 32; m; m >>= 1){ s += __shfl_xor(s, m); mx = fmaxf(mx, __shfl_xor(mx, m)); }
  __shared__ float ss[4], sm[4];
  int w = threadIdx.x >> 6;
  if ((threadIdx.x & 63) == 0){ ss[w] = s; sm[w] = mx; }
  __syncthreads();
  if (threadIdx.x == 0){
    s = ss[0]+ss[1]+ss[2]+ss[3];
    mx = fmaxf(fmaxf(sm[0],sm[1]), fmaxf(sm[2],sm[3]));
    cavg[(mod*B_+b)*C_ + c] = s*(1.f/(float)N_);
    cmax[(mod*B_+b)*C_ + c] = mx;
  }
}

// ---------------- 4. 7x7 conv (2->1) + sigmoid ----------------
__global__ void k_conv7(const float* sconv, const float* rgb_sa_w, const float* rgb_sa_b,
                        const float* chm_sa_w, const float* chm_sa_b, float* sa){
  int mod = blockIdx.y;
  int idx = blockIdx.x*256 + threadIdx.x;
  int b = idx / N_, pix = idx % N_;
  int y = pix / WW, x = pix % WW;
  const float* w7 = mod ? chm_sa_w : rgb_sa_w;
  float acc = (mod ? chm_sa_b : rgb_sa_b)[0];
  const float* sin0 = sconv + (size_t)(mod*B_+b)*2*N_;
  #pragma unroll
  for (int ic = 0; ic < 2; ++ic)
    for (int ky = 0; ky < 7; ++ky){
      int yy = y + ky - 3; if (yy < 0 || yy >= HH) continue;
      for (int kx = 0; kx < 7; ++kx){
        int xx = x + kx - 3; if (xx < 0 || xx >= WW) continue;
        acc += w7[(ic*7+ky)*7+kx] * sin0[ic*N_ + yy*WW + xx];
      }
    }
  sa[(mod*B_+b)*N_ + pix] = sigm(acc);
}

// ---------------- 5. channel-attn MLP ----------------
__global__ void k_ca(const float* cavg, const float* cmax,
                     const float* rw1, const float* rb1, const float* rw2, const float* rb2,
                     const float* cw1, const float* cb1, const float* cw2, const float* cb2,
                     float* ca){
  int mod = blockIdx.x >> 3, b = blockIdx.x & 7;
  const float* w1 = mod ? cw1 : rw1;  const float* b1 = mod ? cb1 : rb1;
  const float* w2 = mod ? cw2 : rw2;  const float* b2 = mod ? cb2 : rb2;
  __shared__ float va[256], vm[256], h1a[16], h1m[16];
  int t = threadIdx.x;
  va[t] = cavg[(mod*B_+b)*C_ + t];
  vm[t] = cmax[(mod*B_+b)*C_ + t];
  __syncthreads();
  if (t < 32){
    int j = t & 15;
    const float* v = (t >= 16) ? vm : va;
    float s = b1[j];
    for (int c = 0; c < 256; ++c) s += w1[j*256+c]*v[c];
    float* hp = (t >= 16) ? h1m : h1a;
    hp[j] = fmaxf(s, 0.f);
  }
  __syncthreads();
  float fa = b2[t], fm = b2[t];
  #pragma unroll
  for (int j = 0; j < 16; ++j){ fa += w2[t*16+j]*h1a[j]; fm += w2[t*16+j]*h1m[j]; }
  ca[(mod*B_+b)*C_ + t] = sigm(fa + fm);
}

// ---------------- 6. q/k/v projections (MFMA, LDS-staged X) ----------------
__global__ __launch_bounds__(256, 2) void k_proj(
                       const float* rgb, const float* chm, const unsigned short* wproj,
                       const float* rq_b, const float* rk_b, const float* rv_b,
                       const float* dq_b, const float* dk_b, const float* dv_b,
                       unsigned short* wsu){
  int mod = blockIdx.z, b = blockIdx.y;
  int pix0 = blockIdx.x * 64;
  const float* X = (mod ? chm : rgb) + (size_t)b*C_*N_;
  const unsigned short* Wm = wproj + (size_t)mod*320*256;
  int lane = threadIdx.x & 63, w = threadIdx.x >> 6;
  int l15 = lane & 15, g = lane >> 4;
  __shared__ unsigned short xs[32*68];   // [k 32][m 64] bf16, pitch 68
  int srow = threadIdx.x >> 3, scol = (threadIdx.x & 7)*8;
  f32x4 acc[5][4];
  #pragma unroll
  for (int i = 0; i < 5; ++i)
    #pragma unroll
    for (int j = 0; j < 4; ++j) acc[i][j] = 0.f;
  for (int k0 = 0; k0 < 256; k0 += 32){
    const float* sp = X + (size_t)(k0 + srow)*N_ + pix0 + scol;
    float4 v0 = *(const float4*)sp;
    float4 v1 = *(const float4*)(sp + 4);
    u16x4 h0 = { f2bf(v0.x), f2bf(v0.y), f2bf(v0.z), f2bf(v0.w) };
    u16x4 h1 = { f2bf(v1.x), f2bf(v1.y), f2bf(v1.z), f2bf(v1.w) };
    __syncthreads();
    *(u16x4*)(xs + srow*68 + scol) = h0;
    *(u16x4*)(xs + srow*68 + scol + 4) = h1;
    __syncthreads();
    bf16x8 af[5];
    #pragma unroll
    for (int cf = 0; cf < 5; ++cf)
      af[cf] = *(const bf16x8*)(Wm + (size_t)(w*80 + cf*16 + l15)*256 + k0 + g*8);
    bf16x8 bx[4];
    #pragma unroll
    for (int mf = 0; mf < 4; ++mf)
      #pragma unroll
      for (int j = 0; j < 8; ++j)
        bx[mf][j] = (short)xs[(g*8+j)*68 + mf*16 + l15];
    #pragma unroll
    for (int cf = 0; cf < 5; ++cf)
      #pragma unroll
      for (int mf = 0; mf < 4; ++mf)
        acc[cf][mf] = __builtin_amdgcn_mfma_f32_16x16x32_bf16(af[cf], bx[mf], acc[cf][mf], 0, 0, 0);
  }
  const float* qb = mod ? dq_b : rq_b;
  const float* kb = mod ? dk_b : rk_b;
  const float* vb = mod ? dv_b : rv_b;
  unsigned short* qT = wsu + (mod ? OFF_DQT : OFF_RQT)/2;
  unsigned short* kT = wsu + (mod ? OFF_DKT : OFF_RKT)/2;
  unsigned short* vB = wsu + (mod ? OFF_DV  : OFF_RV )/2;
  #pragma unroll
  for (int cf = 0; cf < 5; ++cf)
    #pragma unroll
    for (int mf = 0; mf < 4; ++mf){
      int col = pix0 + mf*16 + l15;
      #pragma unroll
      for (int r = 0; r < 4; ++r){
        int o = w*80 + cf*16 + g*4 + r;
        float v = acc[cf][mf][r];
        if (o < 32)       qT[(size_t)(b*N_ + col)*32 + o]        = f2bf(v + qb[o]);
        else if (o < 64)  kT[(size_t)(b*N_ + col)*32 + (o-32)]   = f2bf(v + kb[o-32]);
        else              vB[((size_t)b*C_ + (o-64))*N_ + col]   = f2bf(v + vb[o-64]);
      }
    }
}

// ---------------- 7. softmax row stats: per-lane raw accumulation ----------------
__global__ void k_phase_a(const unsigned short* wsu, float* Mbuf, float* Linv){
  int a = blockIdx.z, b = blockIdx.y;
  int lane = threadIdx.x & 63, w = threadIdx.x >> 6;
  int l15 = lane & 15, g = lane >> 4;
  int n0 = blockIdx.x*64 + w*16;
  const unsigned short* Q = wsu + (a ? OFF_DQT : OFF_RQT)/2;
  const unsigned short* K = wsu + (a ? OFF_RKT : OFF_DKT)/2;
  bf16x8 af = *(const bf16x8*)(Q + (size_t)(b*N_ + n0 + l15)*32 + g*8);
  float mrun[4] = {-INFINITY,-INFINITY,-INFINITY,-INFINITY};
  float lrun[4] = {0.f,0.f,0.f,0.f};
  for (int m0 = 0; m0 < N_; m0 += 64){
    f32x4 d[4];
    #pragma unroll
    for (int s = 0; s < 4; ++s){
      bf16x8 bk = *(const bf16x8*)(K + (size_t)(b*N_ + m0 + s*16 + l15)*32 + g*8);
      f32x4 z = 0.f;
      d[s] = __builtin_amdgcn_mfma_f32_16x16x32_bf16(af, bk, z, 0, 0, 0);
    }
    #pragma unroll
    for (int r = 0; r < 4; ++r){
      float e0 = d[0][r]*QK_SCALE, e1 = d[1][r]*QK_SCALE;
      float e2 = d[2][r]*QK_SCALE, e3 = d[3][r]*QK_SCALE;
      mrun[r] = fmaxf(mrun[r], fmaxf(fmaxf(e0,e1), fmaxf(e2,e3)));
      lrun[r] += (__expf(e0)+__expf(e1)) + (__expf(e2)+__expf(e3));
    }
  }
  #pragma unroll
  for (int r = 0; r < 4; ++r){
    #pragma unroll
    for (int msk = 1; msk < 16; msk <<= 1){
      mrun[r] = fmaxf(mrun[r], __shfl_xor(mrun[r], msk));
      lrun[r] += __shfl_xor(lrun[r], msk);
    }
  }
  if (l15 == 0){
    #pragma unroll
    for (int r = 0; r < 4; ++r){
      int n = n0 + g*4 + r;
      Mbuf[(a*B_+b)*N_ + n] = mrun[r];
      Linv[(a*B_+b)*N_ + n] = __expf(mrun[r]) / lrun[r];   // p = exp(e-M)*Linv = exp(e)/sum
    }
  }
}

// ---------------- 8. phase B: full-C blocks, dbuf P, 1 barrier/iter ----------------
__global__ __launch_bounds__(256, 3) void k_phase_b(
                          const unsigned short* wsu, const float* Mbuf, const float* Linv,
                          unsigned short* att){
  int a = blockIdx.z, b = blockIdx.y, m0 = blockIdx.x*64;
  int lane = threadIdx.x & 63, w = threadIdx.x >> 6;
  int l15 = lane & 15, g = lane >> 4;
  int qn = (w >> 1)*32, qm = (w & 1)*32;   // this wave's P quadrant
  const unsigned short* Q = wsu + (a ? OFF_DQT : OFF_RQT)/2;
  const unsigned short* K = wsu + (a ? OFF_RKT : OFF_DKT)/2;
  const unsigned short* V = wsu + (a ? OFF_DV  : OFF_RV )/2;
  const float* Mr = Mbuf + (size_t)(a*B_+b)*N_;
  const float* Lr = Linv + (size_t)(a*B_+b)*N_;
  __shared__ __align__(16) unsigned char plds[2][64*128];  // [buf][m 64][128B], xor swizzle

  bf16x8 kb[2];
  #pragma unroll
  for (int s = 0; s < 2; ++s)
    kb[s] = *(const bf16x8*)(K + (size_t)(b*N_ + m0 + qm + s*16 + l15)*32 + g*8);

  f32x4 acc[4][4];
  #pragma unroll
  for (int i = 0; i < 4; ++i)
    #pragma unroll
    for (int j = 0; j < 4; ++j) acc[i][j] = 0.f;

  auto computeP = [&](int n0, int buf){
    bf16x8 qa[2]; float4 M4[2], L4[2];
    #pragma unroll
    for (int fr = 0; fr < 2; ++fr){
      int nb = n0 + qn + fr*16;
      qa[fr] = *(const bf16x8*)(Q + (size_t)(b*N_ + nb + l15)*32 + g*8);
      M4[fr] = *(const float4*)(Mr + nb + g*4);
      L4[fr] = *(const float4*)(Lr + nb + g*4);
    }
    #pragma unroll
    for (int fr = 0; fr < 2; ++fr)
      #pragma unroll
      for (int fm = 0; fm < 2; ++fm){
        f32x4 z = 0.f;
        f32x4 d = __builtin_amdgcn_mfma_f32_16x16x32_bf16(qa[fr], kb[fm], z, 0, 0, 0);
        int ml = qm + fm*16 + l15;
        unsigned char* row = plds[buf] + ml*128;
        int sw = (ml & 7) << 4;
        #pragma unroll
        for (int r = 0; r < 4; ++r){
          float mv = (&M4[fr].x)[r], lv = (&L4[fr].x)[r];
          float p = __expf(d[r]*QK_SCALE - mv) * lv;
          int nl = qn + fr*16 + g*4 + r;
          *(unsigned short*)(row + ((nl*2) ^ sw)) = f2bf(p);
        }
      }
  };

  computeP(0, 0);
  __syncthreads();
  for (int t = 0; t < 36; ++t){
    int n0 = t*64;
    if (t < 35) computeP(n0 + 64, (t+1)&1);
    const unsigned char* pbuf = plds[t & 1];
    #pragma unroll
    for (int ks = 0; ks < 2; ++ks){
      bf16x8 pb[4];
      #pragma unroll
      for (int mf = 0; mf < 4; ++mf){
        int ml = mf*16 + l15;
        pb[mf] = *(const bf16x8*)(pbuf + ml*128 + (((ks*32 + g*8)*2) ^ ((ml&7)<<4)));
      }
      __builtin_amdgcn_s_setprio(1);
      #pragma unroll
      for (int cf = 0; cf < 4; ++cf){
        bf16x8 av = *(const bf16x8*)(V + ((size_t)b*C_ + w*64 + cf*16 + l15)*N_ + n0 + ks*32 + g*8);
        #pragma unroll
        for (int mf = 0; mf < 4; ++mf)
          acc[cf][mf] = __builtin_amdgcn_mfma_f32_16x16x32_bf16(av, pb[mf], acc[cf][mf], 0, 0, 0);
      }
      __builtin_amdgcn_s_setprio(0);
    }
    __syncthreads();
  }
  #pragma unroll
  for (int cf = 0; cf < 4; ++cf)
    #pragma unroll
    for (int mf = 0; mf < 4; ++mf)
      #pragma unroll
      for (int r = 0; r < 4; ++r){
        int c = w*64 + cf*16 + g*4 + r;
        int m = m0 + mf*16 + l15;
        att[((size_t)b*512 + a*256 + c)*N_ + m] = f2bf(acc[cf][mf][r]);
      }
}

// ---------------- 9. gate GEMM (LDS-staged att tile) + fuse ----------------
__global__ __launch_bounds__(256, 2) void k_gatefuse(
                           const unsigned short* att, const unsigned short* wgate,
                           const float* gate_b, unsigned short* fused){
  int b = blockIdx.y, m0 = blockIdx.x*64;
  int lane = threadIdx.x & 63, w = threadIdx.x >> 6;
  int l15 = lane & 15, g = lane >> 4;
  __shared__ unsigned short ats[64*72];   // [k 64][m 64], pitch 72, xor swz by k-group
  int srow = threadIdx.x >> 2, scol = (threadIdx.x & 3)*16;
  f32x4 acc[4][4];
  #pragma unroll
  for (int i = 0; i < 4; ++i)
    #pragma unroll
    for (int j = 0; j < 4; ++j) acc[i][j] = 0.f;
  const unsigned short* cat = att + (size_t)b*512*N_;
  for (int k0 = 0; k0 < 512; k0 += 64){
    const unsigned short* sp = cat + (size_t)(k0+srow)*N_ + m0 + scol;
    bf16x8 s0 = *(const bf16x8*)(sp);
    bf16x8 s1 = *(const bf16x8*)(sp + 8);
    int sw = ((srow >> 3) & 3) << 4;
    __syncthreads();
    *(bf16x8*)(ats + srow*72 + (scol ^ sw)) = s0;
    *(bf16x8*)(ats + srow*72 + ((scol + 8) ^ sw)) = s1;
    __syncthreads();
    #pragma unroll
    for (int ks = 0; ks < 2; ++ks){
      bf16x8 aw[4];
      #pragma unroll
      for (int of = 0; of < 4; ++of)
        aw[of] = *(const bf16x8*)(wgate + (size_t)(w*64 + of*16 + l15)*512 + k0 + ks*32 + g*8);
      bf16x8 cb[4];
      #pragma unroll
      for (int mf = 0; mf < 4; ++mf)
        #pragma unroll
        for (int j = 0; j < 8; ++j)
          cb[mf][j] = (short)ats[(ks*32 + g*8 + j)*72 + ((mf*16 + l15) ^ (g << 4))];
      #pragma unroll
      for (int of = 0; of < 4; ++of)
        #pragma unroll
        for (int mf = 0; mf < 4; ++mf)
          acc[of][mf] = __builtin_amdgcn_mfma_f32_16x16x32_bf16(aw[of], cb[mf], acc[of][mf], 0, 0, 0);
    }
  }
  #pragma unroll
  for (int of = 0; of < 4; ++of)
    #pragma unroll
    for (int mf = 0; mf < 4; ++mf)
      #pragma unroll
      for (int r = 0; r < 4; ++r){
        int o = w*64 + of*16 + g*4 + r;
        int m = m0 + mf*16 + l15;
        float gg = sigm(acc[of][mf][r] + gate_b[o]);
        float ra = bf2f(att[((size_t)b*512 + o)*N_ + m]);
        float da = bf2f(att[((size_t)b*512 + 256 + o)*N_ + m]);
        float fv = ra*gg + da*(1.f - gg) + ra*da;
        fused[((size_t)b*C_ + o)*N_ + m] = f2bf(fv);
      }
}

// ---------------- 10. mlp -> per-pixel weight ----------------
__global__ void k_mlp(const unsigned short* fused, const float* w1, const float* g1, const float* b1,
                      const float* w2, const float* g2, const float* b2, float* wmap){
  int idx = blockIdx.x*256 + threadIdx.x;
  int b = idx / N_, pix = idx % N_;
  float h[24];
  #pragma unroll
  for (int j = 0; j < 24; ++j) h[j] = 0.f;
  const unsigned short* fp = fused + (size_t)b*C_*N_ + pix;
  for (int c = 0; c < 256; ++c){
    float v = bf2f(fp[(size_t)c*N_]);
    #pragma unroll
    for (int j = 0; j < 24; ++j) h[j] += w1[j*256 + c] * v;
  }
  float s2 = 0.f;
  #pragma unroll
  for (int j = 0; j < 24; ++j){
    float hj = fmaxf(h[j]*(BN_SC*g1[j]) + b1[j], 0.f);
    s2 += w2[j]*hj;
  }
  s2 = s2*(BN_SC*g2[0]) + b2[0];
  wmap[idx] = sigm(sigm(s2));
}

// ---------------- 11. final combine ----------------
__global__ void k_final(const float* rgb, const float* chm, const float* sa, const float* ca,
                        const float* wmap, float* out){
  const int total4 = B_*C_*N_/4;
  for (int i = blockIdx.x*blockDim.x + threadIdx.x; i < total4; i += gridDim.x*blockDim.x){
    int e = i*4;
    int b = e / (C_*N_);
    int rem = e % (C_*N_);
    int c = rem / N_;
    int pix = rem % N_;
    float4 rv = *(const float4*)(rgb + e);
    float4 cv = *(const float4*)(chm + e);
    float4 sc = *(const float4*)(sa + (size_t)(B_ + b)*N_ + pix);
    float4 sr = *(const float4*)(sa + (size_t)b*N_ + pix);
    float4 wm = *(const float4*)(wmap + (size_t)b*N_ + pix);
    float cac = ca[(B_ + b)*C_ + c];
    float car = ca[b*C_ + c];
    float4 o;
    o.x = rv.x*sc.x*cac + cv.x*sr.x*car*wm.x;
    o.y = rv.y*sc.y*cac + cv.y*sr.y*car*wm.y;
    o.z = rv.z*sc.z*cac + cv.z*sr.z*car*wm.z;
    o.w = rv.w*sc.w*cac + cv.w*sr.w*car*wm.w;
    *(float4*)(out + e) = o;
  }
}

extern "C" void kernel_launch(void* const* d_in, const int* in_sizes, int n_in,
                              void* d_out, int out_size, void* d_ws, size_t ws_size,
                              hipStream_t stream){
  if (ws_size < WS_NEEDED) return;
  const float* rgb      = (const float*)d_in[0];
  const float* chm      = (const float*)d_in[1];
  const float* rgb_sa_w = (const float*)d_in[2];
  const float* rgb_sa_b = (const float*)d_in[3];
  const float* chm_sa_w = (const float*)d_in[4];
  const float* chm_sa_b = (const float*)d_in[5];
  const float* rgb_fc1_w= (const float*)d_in[6];
  const float* rgb_fc1_b= (const float*)d_in[7];
  const float* rgb_fc2_w= (const float*)d_in[8];
  const float* rgb_fc2_b= (const float*)d_in[9];
  const float* chm_fc1_w= (const float*)d_in[10];
  const float* chm_fc1_b= (const float*)d_in[11];
  const float* chm_fc2_w= (const float*)d_in[12];
  const float* chm_fc2_b= (const float*)d_in[13];
  const float* rq_w = (const float*)d_in[14];
  const float* rq_b = (const float*)d_in[15];
  const float* rk_w = (const float*)d_in[16];
  const float* rk_b = (const float*)d_in[17];
  const float* rv_w = (const float*)d_in[18];
  const float* rv_b = (const float*)d_in[19];
  const float* dq_w = (const float*)d_in[20];
  const float* dq_b = (const float*)d_in[21];
  const float* dk_w = (const float*)d_in[22];
  const float* dk_b = (const float*)d_in[23];
  const float* dv_w = (const float*)d_in[24];
  const float* dv_b = (const float*)d_in[25];
  const float* gate_w = (const float*)d_in[26];
  const float* gate_b = (const float*)d_in[27];
  const float* mlp1_w = (const float*)d_in[28];
  const float* mlp1_g = (const float*)d_in[29];
  const float* mlp1_b = (const float*)d_in[30];
  const float* mlp2_w = (const float*)d_in[31];
  const float* mlp2_g = (const float*)d_in[32];
  const float* mlp2_b = (const float*)d_in[33];

  char* ws = (char*)d_ws;
  unsigned short* wsu   = (unsigned short*)d_ws;
  float* sconv = (float*)(ws + OFF_SCONV);
  float* sa    = (float*)(ws + OFF_SA);
  float* cavg  = (float*)(ws + OFF_CAVG);
  float* cmax  = (float*)(ws + OFF_CMAX);
  float* ca    = (float*)(ws + OFF_CA);
  float* Mbuf  = (float*)(ws + OFF_M);
  float* Linv  = (float*)(ws + OFF_LINV);
  float* wmap  = (float*)(ws + OFF_WMAP);
  unsigned short* wproj = (unsigned short*)(ws + OFF_WPROJ);
  unsigned short* wgate = (unsigned short*)(ws + OFF_WGATE);
  unsigned short* att   = (unsigned short*)(ws + OFF_ATT);
  unsigned short* fused = (unsigned short*)(ws + OFF_FUSED);

  k_prep_w<<<dim3(1152), dim3(256), 0, stream>>>(rq_w, rk_w, rv_w, dq_w, dk_w, dv_w, gate_w, wproj, wgate);
  k_red_spatial<<<dim3(288,2), dim3(256), 0, stream>>>(rgb, chm, sconv);
  k_red_channel<<<dim3(2048,2), dim3(256), 0, stream>>>(rgb, chm, cavg, cmax);
  k_conv7<<<dim3(72,2), dim3(256), 0, stream>>>(sconv, rgb_sa_w, rgb_sa_b, chm_sa_w, chm_sa_b, sa);
  k_ca<<<dim3(16), dim3(256), 0, stream>>>(cavg, cmax, rgb_fc1_w, rgb_fc1_b, rgb_fc2_w, rgb_fc2_b,
                                           chm_fc1_w, chm_fc1_b, chm_fc2_w, chm_fc2_b, ca);
  k_proj<<<dim3(36,8,2), dim3(256), 0, stream>>>(rgb, chm, wproj, rq_b, rk_b, rv_b, dq_b, dk_b, dv_b, wsu);
  k_phase_a<<<dim3(36,8,2), dim3(256), 0, stream>>>(wsu, Mbuf, Linv);
  k_phase_b<<<dim3(36,8,2), dim3(256), 0, stream>>>(wsu, Mbuf, Linv, att);
  k_gatefuse<<<dim3(36,8), dim3(256), 0, stream>>>(att, wgate, gate_b, fused);
  k_mlp<<<dim3(72), dim3(256), 0, stream>>>(fused, mlp1_w, mlp1_g, mlp1_b, mlp2_w, mlp2_g, mlp2_b, wmap);
  k_final<<<dim3(2048), dim3(256), 0, stream>>>(rgb, chm, sa, ca, wmap, (float*)d_out);
}